// Round 12
// baseline (175.963 us; speedup 1.0000x reference)
//
#include <hip/hip_runtime.h>

typedef unsigned short u16;
typedef __attribute__((ext_vector_type(8))) short s16x8;
typedef __attribute__((ext_vector_type(4))) float f32x4;

__device__ __forceinline__ float bf2f(u16 u) {
  union { unsigned int i; float f; } v; v.i = ((unsigned int)u) << 16; return v.f;
}
__device__ __forceinline__ u16 f2bf(float f) {
  union { float f; unsigned int i; } v; v.f = f;
  unsigned int r = (v.i + 0x7FFFu + ((v.i >> 16) & 1u)) >> 16;
  return (u16)r;
}
__device__ __forceinline__ void async16(const void* g, void* l) {
  __builtin_amdgcn_global_load_lds((const __attribute__((address_space(1))) void*)g,
                                   (__attribute__((address_space(3))) void*)l, 16, 0, 0);
}

// ---------------------------------------------------------------------------
// prep: LDS-tiled 64x64 transposes (f32 [K][N] -> bf16 Bt[N][K]), bias concat,
// x -> bf16 tail of Acat (float4), find_ranges folded in as extra blocks.
// ---------------------------------------------------------------------------
__global__ __launch_bounds__(256) void prep_kernel(
    const float* __restrict__ W_rel, const float* __restrict__ W_root,
    const float* __restrict__ Wq, const float* __restrict__ Wk,
    const float* __restrict__ Wv, const float* __restrict__ Wskip,
    const float* __restrict__ bq, const float* __restrict__ bk,
    const float* __restrict__ bv, const float* __restrict__ bskip,
    const float* __restrict__ x,
    u16* __restrict__ Bt1, u16* __restrict__ Bt2, float* __restrict__ bias2,
    u16* __restrict__ Acat, int Nn,
    const int* __restrict__ dst, int E, int* __restrict__ rs, int* __restrict__ re)
{
  const int b = (int)blockIdx.x;
  const int tid = threadIdx.x;
  if (b < 576) {
    __shared__ float tile[64][65];
    const float* S;
    u16* D;
    int ldD;
    long dbase;
    if (b < 320) {
      const int kt = b >> 3, et = b & 7;
      const int r0 = kt * 64, c0 = et * 64;
      S = (r0 < 2048) ? (W_rel + (long)r0 * 512 + c0)
                      : (W_root + (long)(r0 - 2048) * 512 + c0);
      D = Bt1; ldD = 2560; dbase = (long)c0 * 2560 + r0;
    } else {
      const int b2 = b - 320;
      const int jt = b2 >> 3, kt = b2 & 7;
      const int j0 = jt * 64, k0 = kt * 64;
      const int which = j0 >> 9, col0 = j0 & 511;
      const float* W = (which == 0) ? Wq : (which == 1) ? Wk : (which == 2) ? Wv : Wskip;
      S = W + (long)k0 * 512 + col0;
      D = Bt2; ldD = 512; dbase = (long)j0 * 512 + k0;
    }
    const int lc = tid & 63;
#pragma unroll
    for (int i = 0; i < 16; ++i) {
      const int r = (tid >> 6) * 16 + i;
      tile[r][lc] = S[(long)r * 512 + lc];
    }
    __syncthreads();
    const int oc2 = (tid & 31) * 2;
#pragma unroll
    for (int i = 0; i < 8; ++i) {
      const int orow = (tid >> 5) + i * 8;
      const unsigned int pk = (unsigned int)f2bf(tile[oc2][orow]) |
                              ((unsigned int)f2bf(tile[oc2 + 1][orow]) << 16);
      *(unsigned int*)(D + dbase + (long)orow * ldD + oc2) = pk;
    }
  } else if (b == 576) {
#pragma unroll
    for (int i = 0; i < 8; ++i) {
      const int j = tid + i * 256;
      const int which = j >> 9, col = j & 511;
      const float* bb = (which == 0) ? bq : (which == 1) ? bk : (which == 2) ? bv : bskip;
      bias2[j] = bb[col];
    }
  } else if (b < 4673) {
    const long u = ((long)(b - 577) * 256 + tid) * 4;
    if (u < (long)Nn * 512) {
      const float4 v = *(const float4*)(x + u);
      const unsigned int p0 = (unsigned int)f2bf(v.x) | ((unsigned int)f2bf(v.y) << 16);
      const unsigned int p1 = (unsigned int)f2bf(v.z) | ((unsigned int)f2bf(v.w) << 16);
      unsigned int* dp = (unsigned int*)(Acat + ((long)(u >> 9)) * 2560 + 2048 + (u & 511));
      dp[0] = p0; dp[1] = p1;
    }
  } else {
    const int e = (b - 4673) * 256 + tid;
    if (e < E) {
      const int d = dst[e];
      if (e == 0 || dst[e - 1] != d) rs[d] = e;
      if (e == E - 1 || dst[e + 1] != d) re[d] = e + 1;
    }
  }
}

// ---------------------------------------------------------------------------
// RGCN aggregation: register accumulators, XCD-chunked dst swizzle, bf16 reads.
// ---------------------------------------------------------------------------
__global__ __launch_bounds__(256) void aggregate_kernel(
    const u16* __restrict__ Acat_ro, const int* __restrict__ src,
    const int* __restrict__ etype, const int* __restrict__ rs,
    const int* __restrict__ re, u16* __restrict__ Acat)
{
  __shared__ int s_src[16];
  __shared__ int s_rel[16];
  const int q = (int)gridDim.x >> 3;
  const int bid = (int)blockIdx.x;
  const int i = (bid & 7) * q + (bid >> 3);   // gridDim.x % 8 == 0
  const int tid = threadIdx.x;
  const int s = rs[i];
  int nE = re[i] - s;
  if (nE > 16) nE = 16;
  if (tid < nE) { s_src[tid] = src[s + tid]; s_rel[tid] = etype[s + tid]; }
  __syncthreads();

  float2 acc[4] = {};
  int cnt[4] = {0, 0, 0, 0};
  for (int t = 0; t < nE; ++t) {
    const int sj = s_src[t];
    const int rel = s_rel[t];
    const unsigned int pk = *(const unsigned int*)(Acat_ro + (long)sj * 2560 + 2048 + tid * 2);
    const float vx = bf2f((u16)pk), vy = bf2f((u16)(pk >> 16));
#pragma unroll
    for (int r = 0; r < 4; ++r)
      if (rel == r) { acc[r].x += vx; acc[r].y += vy; cnt[r]++; }
  }

  const long base = (long)i * 2560 + tid * 2;
#pragma unroll
  for (int r = 0; r < 4; ++r) {
    const float inv = 1.0f / fmaxf((float)cnt[r], 1.0f);
    const unsigned int pk = ((unsigned int)f2bf(acc[r].y * inv) << 16) | f2bf(acc[r].x * inv);
    *(unsigned int*)(Acat + base + r * 512) = pk;
  }
}

// ---------------------------------------------------------------------------
// G1 bf16 GEMM (R10 measured-best config): 128x128 tile, BK=64, 8 waves (2x4),
// 2x32KB dbuf LDS (2 blocks/CU), top-of-iter vmcnt(0) drain, STAGE after
// barrier, setprio, XOR swizzle, XCD-chunked blockIdx swizzle.
// ---------------------------------------------------------------------------
__global__ __launch_bounds__(512, 4) void gemm_bt_kernel(
    const u16* __restrict__ A, const u16* __restrict__ Bt,
    const float* __restrict__ bias, u16* __restrict__ C,
    const int M, const int N, const int K)
{
  __shared__ u16 lds[2][2][128 * 64];   // 2 buf x (A,B) x 16KB = 64 KiB
  const int tid = threadIdx.x;
  const int lane = tid & 63, wid = tid >> 6;
  const int nbn = N >> 7;
  const int q = (int)gridDim.x >> 3;
  const int bid = (int)blockIdx.x;
  const int swz = (bid & 7) * q + (bid >> 3);
  const int bm = swz / nbn, bn = swz % nbn;
  const int wr = wid >> 2, wc = wid & 3;   // 2 x 4 wave grid

  f32x4 acc[4][2] = {};

  const int srow = tid >> 3;   // 0..63
  const int sch = tid & 7;     // physical 16B chunk within 128B row
  const long a_row0 = (long)bm * 128;
  const long b_row0 = (long)bn * 128;
  const int lds_wbase = wid * 512;

  auto STAGE = [&](int buf, int kt) {
#pragma unroll
    for (int it = 0; it < 2; ++it) {
      const int row = it * 64 + srow;
      const int lch = sch ^ (row & 7);
      async16(A  + (a_row0 + row) * K + kt + lch * 8, &lds[buf][0][it * 4096 + lds_wbase]);
      async16(Bt + (b_row0 + row) * K + kt + lch * 8, &lds[buf][1][it * 4096 + lds_wbase]);
    }
  };

  const int nt = K >> 6;
  STAGE(0, 0);
  int cur = 0;
  for (int t = 0; t < nt; ++t) {
    asm volatile("s_waitcnt vmcnt(0)" ::: "memory");
    __builtin_amdgcn_s_barrier();
    if (t + 1 < nt) STAGE(cur ^ 1, (t + 1) << 6);   // overlaps compute below
#pragma unroll
    for (int kk = 0; kk < 2; ++kk) {
      s16x8 af[4], bfr[2];
#pragma unroll
      for (int mi = 0; mi < 4; ++mi) {
        const int row = wr * 64 + mi * 16 + (lane & 15);
        const int cb = (kk * 64 + ((lane >> 4) << 4)) ^ ((row & 7) << 4);
        af[mi] = *(const s16x8*)((const char*)&lds[cur][0][0] + row * 128 + cb);
      }
#pragma unroll
      for (int ni = 0; ni < 2; ++ni) {
        const int row = wc * 32 + ni * 16 + (lane & 15);
        const int cb = (kk * 64 + ((lane >> 4) << 4)) ^ ((row & 7) << 4);
        bfr[ni] = *(const s16x8*)((const char*)&lds[cur][1][0] + row * 128 + cb);
      }
      __builtin_amdgcn_s_setprio(1);
#pragma unroll
      for (int mi = 0; mi < 4; ++mi)
#pragma unroll
        for (int ni = 0; ni < 2; ++ni)
          acc[mi][ni] = __builtin_amdgcn_mfma_f32_16x16x32_bf16(af[mi], bfr[ni], acc[mi][ni], 0, 0, 0);
      __builtin_amdgcn_s_setprio(0);
    }
    cur ^= 1;
  }

#pragma unroll
  for (int mi = 0; mi < 4; ++mi) {
    const int row0 = bm * 128 + wr * 64 + mi * 16 + ((lane >> 4) << 2);
#pragma unroll
    for (int ni = 0; ni < 2; ++ni) {
      const int col = bn * 128 + wc * 32 + ni * 16 + (lane & 15);
      const float bv = bias[col];
#pragma unroll
      for (int j = 0; j < 4; ++j)
        C[(long)(row0 + j) * N + col] = f2bf(acc[mi][ni][j] + bv);
    }
  }
}

// ---------------------------------------------------------------------------
// G2 bf16 GEMM — 8-phase 256² template (R6, measured win). Unchanged.
// ---------------------------------------------------------------------------
__global__ __launch_bounds__(512, 2) void gemm256_kernel(
    const u16* __restrict__ A, const u16* __restrict__ Bt,
    const float* __restrict__ bias, u16* __restrict__ C,
    const int M, const int N, const int K)
{
  __shared__ u16 lds[2][2][256 * 64];   // 2 buf x (A,B) x 32KB = 128 KiB
  const int tid = threadIdx.x;
  const int lane = tid & 63, wid = tid >> 6;
  const int nbn = N >> 8;
  const int q = (int)gridDim.x >> 3;
  const int bid = (int)blockIdx.x;
  const int swz = (bid & 7) * q + (bid >> 3);
  const int bm = swz / nbn, bn = swz % nbn;
  const int wr = wid >> 2, wc = wid & 3;   // 2 x 4 wave grid, wave tile 128x64

  f32x4 acc[8][4] = {};

  const int srow = tid >> 3;   // 0..63
  const int sch = tid & 7;
  const long a_row0 = (long)bm * 256;
  const long b_row0 = (long)bn * 256;
  const int lds_wbase = wid * 512;

  auto STAGE = [&](int buf, int kt) {
#pragma unroll
    for (int it = 0; it < 4; ++it) {
      const int row = it * 64 + srow;              // row & 7 == srow & 7
      const int lch = sch ^ (srow & 7);
      async16(A  + (a_row0 + row) * K + kt + lch * 8, &lds[buf][0][it * 4096 + lds_wbase]);
      async16(Bt + (b_row0 + row) * K + kt + lch * 8, &lds[buf][1][it * 4096 + lds_wbase]);
    }
  };

  const int nt = K >> 6;   // 8 for K=512
  STAGE(0, 0);
  int cur = 0;
  for (int t = 0; t < nt; ++t) {
    asm volatile("s_waitcnt vmcnt(0)" ::: "memory");
    __builtin_amdgcn_s_barrier();
    s16x8 bfr[4][2];
#pragma unroll
    for (int p = 0; p < 4; ++p) {
      s16x8 af[2][2];
#pragma unroll
      for (int i2 = 0; i2 < 2; ++i2) {
        const int row = wr * 128 + (p * 2 + i2) * 16 + (lane & 15);
#pragma unroll
        for (int kk = 0; kk < 2; ++kk) {
          const int cb = (kk * 64 + ((lane >> 4) << 4)) ^ ((row & 7) << 4);
          af[i2][kk] = *(const s16x8*)((const char*)&lds[cur][0][0] + row * 128 + cb);
        }
      }
      if (p == 0) {
#pragma unroll
        for (int ni = 0; ni < 4; ++ni) {
          const int row = wc * 64 + ni * 16 + (lane & 15);
#pragma unroll
          for (int kk = 0; kk < 2; ++kk) {
            const int cb = (kk * 64 + ((lane >> 4) << 4)) ^ ((row & 7) << 4);
            bfr[ni][kk] = *(const s16x8*)((const char*)&lds[cur][1][0] + row * 128 + cb);
          }
        }
        if (t + 1 < nt) STAGE(cur ^ 1, (t + 1) << 6);   // issue-early, drain next iter
      }
      __builtin_amdgcn_s_barrier();
      asm volatile("s_waitcnt lgkmcnt(0)" ::: "memory");
      __builtin_amdgcn_sched_barrier(0);
      __builtin_amdgcn_s_setprio(1);
#pragma unroll
      for (int i2 = 0; i2 < 2; ++i2)
#pragma unroll
        for (int ni = 0; ni < 4; ++ni)
#pragma unroll
          for (int kk = 0; kk < 2; ++kk)
            acc[p * 2 + i2][ni] = __builtin_amdgcn_mfma_f32_16x16x32_bf16(
                af[i2][kk], bfr[ni][kk], acc[p * 2 + i2][ni], 0, 0, 0);
      __builtin_amdgcn_s_setprio(0);
      __builtin_amdgcn_s_barrier();
    }
    cur ^= 1;
  }

#pragma unroll
  for (int mi = 0; mi < 8; ++mi) {
    const int row0 = bm * 256 + wr * 128 + mi * 16 + ((lane >> 4) << 2);
#pragma unroll
    for (int ni = 0; ni < 4; ++ni) {
      const int col = bn * 256 + wc * 64 + ni * 16 + (lane & 15);
      const float bv = bias[col];
#pragma unroll
      for (int j = 0; j < 4; ++j)
        C[(long)(row0 + j) * N + col] = f2bf(acc[mi][ni][j] + bv);
    }
  }
}

// ---------------------------------------------------------------------------
// Wave-per-dst attention + skip + leaky + residual + LayerNorm (R9 win).
// ---------------------------------------------------------------------------
__global__ __launch_bounds__(256) void attn_wave_kernel(
    const u16* __restrict__ qkvs, const int* __restrict__ src,
    const int* __restrict__ rs, const int* __restrict__ re,
    const float* __restrict__ x, const float* __restrict__ gamma,
    const float* __restrict__ beta, float* __restrict__ out,
    float* __restrict__ scl)
{
  __shared__ float sm[4][16];
  __shared__ int s_src[4][16];
  const int bid = (int)blockIdx.x;
  const int tid = threadIdx.x;
  const int lane = tid & 63, wid = tid >> 6;
  const int q = (int)gridDim.x >> 3;            // grid % 8 == 0 (2048)
  const int blk = (bid & 7) * q + (bid >> 3);   // XCD-chunked
  const int i = blk * 4 + wid;                  // this wave's dst node
  if (bid == 0 && tid == 0) scl[0] = 0.0f;      // graph_cl_loss output

  const int s0 = rs[i];
  int ne = re[i] - s0;
  if (ne > 16) ne = 16;
  const int g16 = lane & 15;     // dim-group lane
  const int eg  = lane >> 4;     // edge subgroup 0..3
  if (lane < ne) s_src[wid][lane] = src[s0 + lane];   // same-wave LDS, no barrier

  float qv[32];
#pragma unroll
  for (int c = 0; c < 4; ++c) {
    const s16x8 q8 = *(const s16x8*)(qkvs + (long)i * 2048 + c * 128 + g16 * 8);
#pragma unroll
    for (int u = 0; u < 8; ++u) qv[c * 8 + u] = bf2f((u16)q8[u]);
  }

#pragma unroll
  for (int round = 0; round < 4; ++round) {
    const int e = round * 4 + eg;
    float dp = 0.f;
    if (e < ne) {
      const long rb = (long)s_src[wid][e] * 2048 + 512;
#pragma unroll
      for (int c = 0; c < 4; ++c) {
        const s16x8 k8 = *(const s16x8*)(qkvs + rb + c * 128 + g16 * 8);
#pragma unroll
        for (int u = 0; u < 8; ++u) dp += qv[c * 8 + u] * bf2f((u16)k8[u]);
      }
    }
#pragma unroll
    for (int m = 1; m <= 8; m <<= 1) dp += __shfl_xor(dp, m);
    if (g16 == 0 && e < ne) sm[wid][e] = dp * 0.04419417382415922f;  // 1/sqrt(512)
  }
  {
    const float v = (lane < ne) ? sm[wid][lane] : -1e30f;
    float mx = v;
#pragma unroll
    for (int m = 1; m <= 8; m <<= 1) mx = fmaxf(mx, __shfl_xor(mx, m, 16));
    const float ex = (lane < ne) ? expf(v - mx) : 0.f;
    float den = ex;
#pragma unroll
    for (int m = 1; m <= 8; m <<= 1) den += __shfl_xor(den, m, 16);
    if (lane < ne) sm[wid][lane] = ex / fmaxf(den, 1e-16f);
  }

  const int d8 = lane * 8;
  float a[8] = {};
  for (int e = 0; e < ne; ++e) {
    const float al = sm[wid][e];
    const s16x8 v8 = *(const s16x8*)(qkvs + (long)s_src[wid][e] * 2048 + 1024 + d8);
#pragma unroll
    for (int u = 0; u < 8; ++u) a[u] += al * bf2f((u16)v8[u]);
  }
  const s16x8 sk8 = *(const s16x8*)(qkvs + (long)i * 2048 + 1536 + d8);
  const float4 x0 = *(const float4*)(x + (long)i * 512 + d8);
  const float4 x1 = *(const float4*)(x + (long)i * 512 + d8 + 4);
  float o[8];
  float s = 0.f, s2 = 0.f;
#pragma unroll
  for (int u = 0; u < 8; ++u) {
    float h = a[u] + bf2f((u16)sk8[u]);
    h = (h > 0.f) ? h : 0.01f * h;
    const float xx = (u < 4) ? ((const float*)&x0)[u] : ((const float*)&x1)[u - 4];
    o[u] = xx + h;
    s += o[u];
    s2 += o[u] * o[u];
  }
#pragma unroll
  for (int m = 32; m >= 1; m >>= 1) { s += __shfl_xor(s, m); s2 += __shfl_xor(s2, m); }
  const float mean = s * (1.f / 512.f);
  const float var = s2 * (1.f / 512.f) - mean * mean;
  const float rstd = rsqrtf(var + 1e-5f);
  const float4 g0 = *(const float4*)(gamma + d8), g1 = *(const float4*)(gamma + d8 + 4);
  const float4 b0 = *(const float4*)(beta + d8),  b1 = *(const float4*)(beta + d8 + 4);
  float4 r0, r1;
  r0.x = (o[0] - mean) * rstd * g0.x + b0.x;
  r0.y = (o[1] - mean) * rstd * g0.y + b0.y;
  r0.z = (o[2] - mean) * rstd * g0.z + b0.z;
  r0.w = (o[3] - mean) * rstd * g0.w + b0.w;
  r1.x = (o[4] - mean) * rstd * g1.x + b1.x;
  r1.y = (o[5] - mean) * rstd * g1.y + b1.y;
  r1.z = (o[6] - mean) * rstd * g1.z + b1.z;
  r1.w = (o[7] - mean) * rstd * g1.w + b1.w;
  *(float4*)(out + (long)i * 512 + d8) = r0;
  *(float4*)(out + (long)i * 512 + d8 + 4) = r1;
}

// ---------------------------------------------------------------------------
// ISOLATION ROUND: G1 launched 3x (idempotent). G1 = (dur - 114.8)/2.
// ---------------------------------------------------------------------------
extern "C" void kernel_launch(void* const* d_in, const int* in_sizes, int n_in,
                              void* d_out, int out_size, void* d_ws, size_t ws_size,
                              hipStream_t stream) {
  const float* x      = (const float*)d_in[0];
  const int*   ei     = (const int*)d_in[1];
  const int*   et     = (const int*)d_in[2];
  const float* W_rel  = (const float*)d_in[3];
  const float* W_root = (const float*)d_in[4];
  const float* b_rgcn = (const float*)d_in[5];
  const float* Wq     = (const float*)d_in[6];
  const float* bq     = (const float*)d_in[7];
  const float* Wk     = (const float*)d_in[8];
  const float* bk     = (const float*)d_in[9];
  const float* Wv     = (const float*)d_in[10];
  const float* bv     = (const float*)d_in[11];
  const float* Wskip  = (const float*)d_in[12];
  const float* bskip  = (const float*)d_in[13];
  const float* gamma  = (const float*)d_in[14];
  const float* beta   = (const float*)d_in[15];
  const int E  = in_sizes[2];
  const int Nn = in_sizes[0] / 512;           // 8192
  const int* srcA = ei;
  const int* dstA = ei + E;

  char* p = (char*)d_ws;
  u16* Acat   = (u16*)p;   p += (size_t)Nn * 2560 * 2;   // [N][2560] bf16
  u16* Bt1    = (u16*)p;   p += (size_t)512 * 2560 * 2;  // [512][2560] bf16
  u16* Bt2    = (u16*)p;   p += (size_t)2048 * 512 * 2;  // [2048][512] bf16
  float* bias2= (float*)p; p += (size_t)2048 * 4;
  u16* ho     = (u16*)p;   p += (size_t)Nn * 512 * 2;
  u16* qkvs   = (u16*)p;   p += (size_t)Nn * 2048 * 2;
  int* rs     = (int*)p;   p += (size_t)Nn * 4;
  int* re     = (int*)p;   p += (size_t)Nn * 4;

  const int FB = (E + 255) / 256;
  const int prep_blocks = 4673 + FB;

  prep_kernel<<<prep_blocks, 256, 0, stream>>>(W_rel, W_root, Wq, Wk, Wv, Wskip,
                                               bq, bk, bv, bskip, x, Bt1, Bt2, bias2, Acat, Nn,
                                               dstA, E, rs, re);
  aggregate_kernel<<<Nn, 256, 0, stream>>>(Acat, srcA, et, rs, re, Acat);
  // G1 x3 — idempotent; isolates G1's cost: G1 = (dur - 114.8)/2
  gemm_bt_kernel<<<(Nn / 128) * (512 >> 7), 512, 0, stream>>>(Acat, Bt1, b_rgcn, ho, Nn, 512, 2560);
  gemm_bt_kernel<<<(Nn / 128) * (512 >> 7), 512, 0, stream>>>(Acat, Bt1, b_rgcn, ho, Nn, 512, 2560);
  gemm_bt_kernel<<<(Nn / 128) * (512 >> 7), 512, 0, stream>>>(Acat, Bt1, b_rgcn, ho, Nn, 512, 2560);
  gemm256_kernel<<<(Nn / 256) * (2048 >> 8), 512, 0, stream>>>(ho, Bt2, bias2, qkvs, Nn, 2048, 512);
  attn_wave_kernel<<<Nn / 4, 256, 0, stream>>>(qkvs, srcA, rs, re, x, gamma, beta,
                                               (float*)d_out, (float*)d_out + (size_t)Nn * 512);
}

// Round 13
// 119.250 us; speedup vs baseline: 1.4756x; 1.4756x over previous
//
#include <hip/hip_runtime.h>

typedef unsigned short u16;
typedef __attribute__((ext_vector_type(8))) short s16x8;
typedef __attribute__((ext_vector_type(4))) float f32x4;

__device__ __forceinline__ float bf2f(u16 u) {
  union { unsigned int i; float f; } v; v.i = ((unsigned int)u) << 16; return v.f;
}
__device__ __forceinline__ u16 f2bf(float f) {
  union { float f; unsigned int i; } v; v.f = f;
  unsigned int r = (v.i + 0x7FFFu + ((v.i >> 16) & 1u)) >> 16;
  return (u16)r;
}
__device__ __forceinline__ void async16(const void* g, void* l) {
  __builtin_amdgcn_global_load_lds((const __attribute__((address_space(1))) void*)g,
                                   (__attribute__((address_space(3))) void*)l, 16, 0, 0);
}

// ---------------------------------------------------------------------------
// prep: LDS-tiled 64x64 transposes (f32 [K][N] -> bf16 Bt[N][K]), bias concat,
// x -> bf16 tail of Acat (float4), find_ranges folded in as extra blocks.
// ---------------------------------------------------------------------------
__global__ __launch_bounds__(256) void prep_kernel(
    const float* __restrict__ W_rel, const float* __restrict__ W_root,
    const float* __restrict__ Wq, const float* __restrict__ Wk,
    const float* __restrict__ Wv, const float* __restrict__ Wskip,
    const float* __restrict__ bq, const float* __restrict__ bk,
    const float* __restrict__ bv, const float* __restrict__ bskip,
    const float* __restrict__ x,
    u16* __restrict__ Bt1, u16* __restrict__ Bt2, float* __restrict__ bias2,
    u16* __restrict__ Acat, int Nn,
    const int* __restrict__ dst, int E, int* __restrict__ rs, int* __restrict__ re)
{
  const int b = (int)blockIdx.x;
  const int tid = threadIdx.x;
  if (b < 576) {
    __shared__ float tile[64][65];
    const float* S;
    u16* D;
    int ldD;
    long dbase;
    if (b < 320) {
      const int kt = b >> 3, et = b & 7;
      const int r0 = kt * 64, c0 = et * 64;
      S = (r0 < 2048) ? (W_rel + (long)r0 * 512 + c0)
                      : (W_root + (long)(r0 - 2048) * 512 + c0);
      D = Bt1; ldD = 2560; dbase = (long)c0 * 2560 + r0;
    } else {
      const int b2 = b - 320;
      const int jt = b2 >> 3, kt = b2 & 7;
      const int j0 = jt * 64, k0 = kt * 64;
      const int which = j0 >> 9, col0 = j0 & 511;
      const float* W = (which == 0) ? Wq : (which == 1) ? Wk : (which == 2) ? Wv : Wskip;
      S = W + (long)k0 * 512 + col0;
      D = Bt2; ldD = 512; dbase = (long)j0 * 512 + k0;
    }
    const int lc = tid & 63;
#pragma unroll
    for (int i = 0; i < 16; ++i) {
      const int r = (tid >> 6) * 16 + i;
      tile[r][lc] = S[(long)r * 512 + lc];
    }
    __syncthreads();
    const int oc2 = (tid & 31) * 2;
#pragma unroll
    for (int i = 0; i < 8; ++i) {
      const int orow = (tid >> 5) + i * 8;
      const unsigned int pk = (unsigned int)f2bf(tile[oc2][orow]) |
                              ((unsigned int)f2bf(tile[oc2 + 1][orow]) << 16);
      *(unsigned int*)(D + dbase + (long)orow * ldD + oc2) = pk;
    }
  } else if (b == 576) {
#pragma unroll
    for (int i = 0; i < 8; ++i) {
      const int j = tid + i * 256;
      const int which = j >> 9, col = j & 511;
      const float* bb = (which == 0) ? bq : (which == 1) ? bk : (which == 2) ? bv : bskip;
      bias2[j] = bb[col];
    }
  } else if (b < 4673) {
    const long u = ((long)(b - 577) * 256 + tid) * 4;
    if (u < (long)Nn * 512) {
      const float4 v = *(const float4*)(x + u);
      const unsigned int p0 = (unsigned int)f2bf(v.x) | ((unsigned int)f2bf(v.y) << 16);
      const unsigned int p1 = (unsigned int)f2bf(v.z) | ((unsigned int)f2bf(v.w) << 16);
      unsigned int* dp = (unsigned int*)(Acat + ((long)(u >> 9)) * 2560 + 2048 + (u & 511));
      dp[0] = p0; dp[1] = p1;
    }
  } else {
    const int e = (b - 4673) * 256 + tid;
    if (e < E) {
      const int d = dst[e];
      if (e == 0 || dst[e - 1] != d) rs[d] = e;
      if (e == E - 1 || dst[e + 1] != d) re[d] = e + 1;
    }
  }
}

// ---------------------------------------------------------------------------
// RGCN aggregation: register accumulators, XCD-chunked dst swizzle, bf16 reads.
// ---------------------------------------------------------------------------
__global__ __launch_bounds__(256) void aggregate_kernel(
    const u16* __restrict__ Acat_ro, const int* __restrict__ src,
    const int* __restrict__ etype, const int* __restrict__ rs,
    const int* __restrict__ re, u16* __restrict__ Acat)
{
  __shared__ int s_src[16];
  __shared__ int s_rel[16];
  const int q = (int)gridDim.x >> 3;
  const int bid = (int)blockIdx.x;
  const int i = (bid & 7) * q + (bid >> 3);   // gridDim.x % 8 == 0
  const int tid = threadIdx.x;
  const int s = rs[i];
  int nE = re[i] - s;
  if (nE > 16) nE = 16;
  if (tid < nE) { s_src[tid] = src[s + tid]; s_rel[tid] = etype[s + tid]; }
  __syncthreads();

  float2 acc[4] = {};
  int cnt[4] = {0, 0, 0, 0};
  for (int t = 0; t < nE; ++t) {
    const int sj = s_src[t];
    const int rel = s_rel[t];
    const unsigned int pk = *(const unsigned int*)(Acat_ro + (long)sj * 2560 + 2048 + tid * 2);
    const float vx = bf2f((u16)pk), vy = bf2f((u16)(pk >> 16));
#pragma unroll
    for (int r = 0; r < 4; ++r)
      if (rel == r) { acc[r].x += vx; acc[r].y += vy; cnt[r]++; }
  }

  const long base = (long)i * 2560 + tid * 2;
#pragma unroll
  for (int r = 0; r < 4; ++r) {
    const float inv = 1.0f / fmaxf((float)cnt[r], 1.0f);
    const unsigned int pk = ((unsigned int)f2bf(acc[r].y * inv) << 16) | f2bf(acc[r].x * inv);
    *(unsigned int*)(Acat + base + r * 512) = pk;
  }
}

// ---------------------------------------------------------------------------
// G1 bf16 GEMM, split-K=2: partial[kh] = A[:, kh*K/2 : (kh+1)*K/2] @ Bt^T.
// Grid 512 (64 bm x 4 bn x 2 kh, XCD-chunked) = 2 blocks/CU. 4 waves (2x2),
// wave tile 64x64 (4x4 frags) -> LDS reads 64KB/tile (vs 96 at 64x32).
// 2x32KB dbuf LDS, R10 schedule: top-of-iter vmcnt(0) drain (loads issued a
// full compute-phase ago), STAGE after barrier, setprio, XOR swizzle.
// Cross-block overlap (2 blk/CU) provides the latency hiding the 4-wave
// config lacked in R4. Partials bf16; bias added in reduce.
// ---------------------------------------------------------------------------
__global__ __launch_bounds__(256, 2) void gemm_splitk_kernel(
    const u16* __restrict__ A, const u16* __restrict__ Bt,
    u16* __restrict__ Cp0, const int M, const int N, const int K)
{
  __shared__ u16 lds[2][2][128 * 64];   // 2 buf x (A,B) x 16KB = 64 KiB
  const int tid = threadIdx.x;
  const int lane = tid & 63, wid = tid >> 6;   // 4 waves
  const int q = (int)gridDim.x >> 3;           // 64
  const int bid = (int)blockIdx.x;
  const int swz = (bid & 7) * q + (bid >> 3);
  const int bm = swz >> 3;
  const int v = swz & 7;
  const int bn = v >> 1, kh = v & 1;
  const int wr = wid >> 1, wc = wid & 1;       // 2 x 2 wave grid

  f32x4 acc[4][4] = {};

  const long a_row0 = (long)bm * 128;
  const long b_row0 = (long)bn * 128;
  const int k0 = kh * (K >> 1);
  const int lrow8 = lane >> 3;    // row within an 8-row instr group
  const int lch   = lane & 7;     // physical chunk within 128B row

  auto STAGE = [&](int buf, int kt) {
#pragma unroll
    for (int it = 0; it < 4; ++it) {
      const int row0 = wid * 32 + it * 8;          // wave-uniform
      const int row  = row0 + lrow8;               // per-lane source row
      const int sch  = lch ^ (row & 7);            // pre-swizzled source chunk
      async16(A  + (a_row0 + row) * K + kt + sch * 8, &lds[buf][0][row0 * 64]);
      async16(Bt + (b_row0 + row) * K + kt + sch * 8, &lds[buf][1][row0 * 64]);
    }
  };

  const int nt = (K >> 1) >> 6;   // 20
  STAGE(0, k0);
  int cur = 0;
  for (int t = 0; t < nt; ++t) {
    // tile t's loads were issued one full compute-phase ago
    asm volatile("s_waitcnt vmcnt(0)" ::: "memory");
    __builtin_amdgcn_s_barrier();
    if (t + 1 < nt) STAGE(cur ^ 1, k0 + ((t + 1) << 6));   // overlaps compute
#pragma unroll
    for (int kk = 0; kk < 2; ++kk) {
      s16x8 af[4], bfr[4];
#pragma unroll
      for (int mi = 0; mi < 4; ++mi) {
        const int row = wr * 64 + mi * 16 + (lane & 15);
        const int cb = (kk * 64 + ((lane >> 4) << 4)) ^ ((row & 7) << 4);
        af[mi] = *(const s16x8*)((const char*)&lds[cur][0][0] + row * 128 + cb);
      }
#pragma unroll
      for (int ni = 0; ni < 4; ++ni) {
        const int row = wc * 64 + ni * 16 + (lane & 15);
        const int cb = (kk * 64 + ((lane >> 4) << 4)) ^ ((row & 7) << 4);
        bfr[ni] = *(const s16x8*)((const char*)&lds[cur][1][0] + row * 128 + cb);
      }
      __builtin_amdgcn_s_setprio(1);
#pragma unroll
      for (int mi = 0; mi < 4; ++mi)
#pragma unroll
        for (int ni = 0; ni < 4; ++ni)
          acc[mi][ni] = __builtin_amdgcn_mfma_f32_16x16x32_bf16(af[mi], bfr[ni], acc[mi][ni], 0, 0, 0);
      __builtin_amdgcn_s_setprio(0);
    }
    cur ^= 1;
  }

  u16* Cp = Cp0 + (long)kh * M * N;
#pragma unroll
  for (int mi = 0; mi < 4; ++mi) {
    const int row0 = bm * 128 + wr * 64 + mi * 16 + ((lane >> 4) << 2);
#pragma unroll
    for (int ni = 0; ni < 4; ++ni) {
      const int col = bn * 128 + wc * 64 + ni * 16 + (lane & 15);
#pragma unroll
      for (int j = 0; j < 4; ++j)
        Cp[(long)(row0 + j) * N + col] = f2bf(acc[mi][ni][j]);
    }
  }
}

// ---------------------------------------------------------------------------
// reduce: ho = ho_part0 + ho_part1 + b_rgcn (bf16 in/out, 16B per thread)
// ---------------------------------------------------------------------------
__global__ __launch_bounds__(256) void reduce_ho_kernel(
    const u16* __restrict__ h0, const u16* __restrict__ h1,
    const float* __restrict__ bias, u16* __restrict__ ho)
{
  const long e8 = ((long)blockIdx.x * 256 + threadIdx.x) * 8;
  const int col = (int)(e8 & 511);
  const s16x8 a = *(const s16x8*)(h0 + e8);
  const s16x8 b = *(const s16x8*)(h1 + e8);
  s16x8 r;
#pragma unroll
  for (int u = 0; u < 8; ++u)
    r[u] = (short)f2bf(bf2f((u16)a[u]) + bf2f((u16)b[u]) + bias[col + u]);
  *(s16x8*)(ho + e8) = r;
}

// ---------------------------------------------------------------------------
// G2 bf16 GEMM — 8-phase 256² template (R6, measured win). Unchanged.
// ---------------------------------------------------------------------------
__global__ __launch_bounds__(512, 2) void gemm256_kernel(
    const u16* __restrict__ A, const u16* __restrict__ Bt,
    const float* __restrict__ bias, u16* __restrict__ C,
    const int M, const int N, const int K)
{
  __shared__ u16 lds[2][2][256 * 64];   // 2 buf x (A,B) x 32KB = 128 KiB
  const int tid = threadIdx.x;
  const int lane = tid & 63, wid = tid >> 6;
  const int nbn = N >> 8;
  const int q = (int)gridDim.x >> 3;
  const int bid = (int)blockIdx.x;
  const int swz = (bid & 7) * q + (bid >> 3);
  const int bm = swz / nbn, bn = swz % nbn;
  const int wr = wid >> 2, wc = wid & 3;   // 2 x 4 wave grid, wave tile 128x64

  f32x4 acc[8][4] = {};

  const int srow = tid >> 3;   // 0..63
  const int sch = tid & 7;
  const long a_row0 = (long)bm * 256;
  const long b_row0 = (long)bn * 256;
  const int lds_wbase = wid * 512;

  auto STAGE = [&](int buf, int kt) {
#pragma unroll
    for (int it = 0; it < 4; ++it) {
      const int row = it * 64 + srow;              // row & 7 == srow & 7
      const int lch = sch ^ (srow & 7);
      async16(A  + (a_row0 + row) * K + kt + lch * 8, &lds[buf][0][it * 4096 + lds_wbase]);
      async16(Bt + (b_row0 + row) * K + kt + lch * 8, &lds[buf][1][it * 4096 + lds_wbase]);
    }
  };

  const int nt = K >> 6;   // 8 for K=512
  STAGE(0, 0);
  int cur = 0;
  for (int t = 0; t < nt; ++t) {
    asm volatile("s_waitcnt vmcnt(0)" ::: "memory");
    __builtin_amdgcn_s_barrier();
    s16x8 bfr[4][2];
#pragma unroll
    for (int p = 0; p < 4; ++p) {
      s16x8 af[2][2];
#pragma unroll
      for (int i2 = 0; i2 < 2; ++i2) {
        const int row = wr * 128 + (p * 2 + i2) * 16 + (lane & 15);
#pragma unroll
        for (int kk = 0; kk < 2; ++kk) {
          const int cb = (kk * 64 + ((lane >> 4) << 4)) ^ ((row & 7) << 4);
          af[i2][kk] = *(const s16x8*)((const char*)&lds[cur][0][0] + row * 128 + cb);
        }
      }
      if (p == 0) {
#pragma unroll
        for (int ni = 0; ni < 4; ++ni) {
          const int row = wc * 64 + ni * 16 + (lane & 15);
#pragma unroll
          for (int kk = 0; kk < 2; ++kk) {
            const int cb = (kk * 64 + ((lane >> 4) << 4)) ^ ((row & 7) << 4);
            bfr[ni][kk] = *(const s16x8*)((const char*)&lds[cur][1][0] + row * 128 + cb);
          }
        }
        if (t + 1 < nt) STAGE(cur ^ 1, (t + 1) << 6);   // issue-early, drain next iter
      }
      __builtin_amdgcn_s_barrier();
      asm volatile("s_waitcnt lgkmcnt(0)" ::: "memory");
      __builtin_amdgcn_sched_barrier(0);
      __builtin_amdgcn_s_setprio(1);
#pragma unroll
      for (int i2 = 0; i2 < 2; ++i2)
#pragma unroll
        for (int ni = 0; ni < 4; ++ni)
#pragma unroll
          for (int kk = 0; kk < 2; ++kk)
            acc[p * 2 + i2][ni] = __builtin_amdgcn_mfma_f32_16x16x32_bf16(
                af[i2][kk], bfr[ni][kk], acc[p * 2 + i2][ni], 0, 0, 0);
      __builtin_amdgcn_s_setprio(0);
      __builtin_amdgcn_s_barrier();
    }
    cur ^= 1;
  }

#pragma unroll
  for (int mi = 0; mi < 8; ++mi) {
    const int row0 = bm * 256 + wr * 128 + mi * 16 + ((lane >> 4) << 2);
#pragma unroll
    for (int ni = 0; ni < 4; ++ni) {
      const int col = bn * 256 + wc * 64 + ni * 16 + (lane & 15);
      const float bv = bias[col];
#pragma unroll
      for (int j = 0; j < 4; ++j)
        C[(long)(row0 + j) * N + col] = f2bf(acc[mi][ni][j] + bv);
    }
  }
}

// ---------------------------------------------------------------------------
// Wave-per-dst attention + skip + leaky + residual + LayerNorm (R9 win).
// ---------------------------------------------------------------------------
__global__ __launch_bounds__(256) void attn_wave_kernel(
    const u16* __restrict__ qkvs, const int* __restrict__ src,
    const int* __restrict__ rs, const int* __restrict__ re,
    const float* __restrict__ x, const float* __restrict__ gamma,
    const float* __restrict__ beta, float* __restrict__ out,
    float* __restrict__ scl)
{
  __shared__ float sm[4][16];
  __shared__ int s_src[4][16];
  const int bid = (int)blockIdx.x;
  const int tid = threadIdx.x;
  const int lane = tid & 63, wid = tid >> 6;
  const int q = (int)gridDim.x >> 3;            // grid % 8 == 0 (2048)
  const int blk = (bid & 7) * q + (bid >> 3);   // XCD-chunked
  const int i = blk * 4 + wid;                  // this wave's dst node
  if (bid == 0 && tid == 0) scl[0] = 0.0f;      // graph_cl_loss output

  const int s0 = rs[i];
  int ne = re[i] - s0;
  if (ne > 16) ne = 16;
  const int g16 = lane & 15;     // dim-group lane
  const int eg  = lane >> 4;     // edge subgroup 0..3
  if (lane < ne) s_src[wid][lane] = src[s0 + lane];   // same-wave LDS, no barrier

  float qv[32];
#pragma unroll
  for (int c = 0; c < 4; ++c) {
    const s16x8 q8 = *(const s16x8*)(qkvs + (long)i * 2048 + c * 128 + g16 * 8);
#pragma unroll
    for (int u = 0; u < 8; ++u) qv[c * 8 + u] = bf2f((u16)q8[u]);
  }

#pragma unroll
  for (int round = 0; round < 4; ++round) {
    const int e = round * 4 + eg;
    float dp = 0.f;
    if (e < ne) {
      const long rb = (long)s_src[wid][e] * 2048 + 512;
#pragma unroll
      for (int c = 0; c < 4; ++c) {
        const s16x8 k8 = *(const s16x8*)(qkvs + rb + c * 128 + g16 * 8);
#pragma unroll
        for (int u = 0; u < 8; ++u) dp += qv[c * 8 + u] * bf2f((u16)k8[u]);
      }
    }
#pragma unroll
    for (int m = 1; m <= 8; m <<= 1) dp += __shfl_xor(dp, m);
    if (g16 == 0 && e < ne) sm[wid][e] = dp * 0.04419417382415922f;  // 1/sqrt(512)
  }
  {
    const float v = (lane < ne) ? sm[wid][lane] : -1e30f;
    float mx = v;
#pragma unroll
    for (int m = 1; m <= 8; m <<= 1) mx = fmaxf(mx, __shfl_xor(mx, m, 16));
    const float ex = (lane < ne) ? expf(v - mx) : 0.f;
    float den = ex;
#pragma unroll
    for (int m = 1; m <= 8; m <<= 1) den += __shfl_xor(den, m, 16);
    if (lane < ne) sm[wid][lane] = ex / fmaxf(den, 1e-16f);
  }

  const int d8 = lane * 8;
  float a[8] = {};
  for (int e = 0; e < ne; ++e) {
    const float al = sm[wid][e];
    const s16x8 v8 = *(const s16x8*)(qkvs + (long)s_src[wid][e] * 2048 + 1024 + d8);
#pragma unroll
    for (int u = 0; u < 8; ++u) a[u] += al * bf2f((u16)v8[u]);
  }
  const s16x8 sk8 = *(const s16x8*)(qkvs + (long)i * 2048 + 1536 + d8);
  const float4 x0 = *(const float4*)(x + (long)i * 512 + d8);
  const float4 x1 = *(const float4*)(x + (long)i * 512 + d8 + 4);
  float o[8];
  float s = 0.f, s2 = 0.f;
#pragma unroll
  for (int u = 0; u < 8; ++u) {
    float h = a[u] + bf2f((u16)sk8[u]);
    h = (h > 0.f) ? h : 0.01f * h;
    const float xx = (u < 4) ? ((const float*)&x0)[u] : ((const float*)&x1)[u - 4];
    o[u] = xx + h;
    s += o[u];
    s2 += o[u] * o[u];
  }
#pragma unroll
  for (int m = 32; m >= 1; m >>= 1) { s += __shfl_xor(s, m); s2 += __shfl_xor(s2, m); }
  const float mean = s * (1.f / 512.f);
  const float var = s2 * (1.f / 512.f) - mean * mean;
  const float rstd = rsqrtf(var + 1e-5f);
  const float4 g0 = *(const float4*)(gamma + d8), g1 = *(const float4*)(gamma + d8 + 4);
  const float4 b0 = *(const float4*)(beta + d8),  b1 = *(const float4*)(beta + d8 + 4);
  float4 r0, r1;
  r0.x = (o[0] - mean) * rstd * g0.x + b0.x;
  r0.y = (o[1] - mean) * rstd * g0.y + b0.y;
  r0.z = (o[2] - mean) * rstd * g0.z + b0.z;
  r0.w = (o[3] - mean) * rstd * g0.w + b0.w;
  r1.x = (o[4] - mean) * rstd * g1.x + b1.x;
  r1.y = (o[5] - mean) * rstd * g1.y + b1.y;
  r1.z = (o[6] - mean) * rstd * g1.z + b1.z;
  r1.w = (o[7] - mean) * rstd * g1.w + b1.w;
  *(float4*)(out + (long)i * 512 + d8) = r0;
  *(float4*)(out + (long)i * 512 + d8 + 4) = r1;
}

// ---------------------------------------------------------------------------
extern "C" void kernel_launch(void* const* d_in, const int* in_sizes, int n_in,
                              void* d_out, int out_size, void* d_ws, size_t ws_size,
                              hipStream_t stream) {
  const float* x      = (const float*)d_in[0];
  const int*   ei     = (const int*)d_in[1];
  const int*   et     = (const int*)d_in[2];
  const float* W_rel  = (const float*)d_in[3];
  const float* W_root = (const float*)d_in[4];
  const float* b_rgcn = (const float*)d_in[5];
  const float* Wq     = (const float*)d_in[6];
  const float* bq     = (const float*)d_in[7];
  const float* Wk     = (const float*)d_in[8];
  const float* bk     = (const float*)d_in[9];
  const float* Wv     = (const float*)d_in[10];
  const float* bv     = (const float*)d_in[11];
  const float* Wskip  = (const float*)d_in[12];
  const float* bskip  = (const float*)d_in[13];
  const float* gamma  = (const float*)d_in[14];
  const float* beta   = (const float*)d_in[15];
  const int E  = in_sizes[2];
  const int Nn = in_sizes[0] / 512;           // 8192
  const int* srcA = ei;
  const int* dstA = ei + E;

  char* p = (char*)d_ws;
  u16* Acat   = (u16*)p;   p += (size_t)Nn * 2560 * 2;   // [N][2560] bf16
  u16* Bt1    = (u16*)p;   p += (size_t)512 * 2560 * 2;  // [512][2560] bf16
  u16* Bt2    = (u16*)p;   p += (size_t)2048 * 512 * 2;  // [2048][512] bf16
  float* bias2= (float*)p; p += (size_t)2048 * 4;
  u16* ho     = (u16*)p;   p += (size_t)Nn * 512 * 2;
  u16* qkvs   = (u16*)p;   p += (size_t)Nn * 2048 * 2;
  int* rs     = (int*)p;   p += (size_t)Nn * 4;
  int* re     = (int*)p;   p += (size_t)Nn * 4;
  u16* hop    = (u16*)p;   p += (size_t)2 * Nn * 512 * 2;  // split-K partials

  const int FB = (E + 255) / 256;
  const int prep_blocks = 4673 + FB;

  prep_kernel<<<prep_blocks, 256, 0, stream>>>(W_rel, W_root, Wq, Wk, Wv, Wskip,
                                               bq, bk, bv, bskip, x, Bt1, Bt2, bias2, Acat, Nn,
                                               dstA, E, rs, re);
  aggregate_kernel<<<Nn, 256, 0, stream>>>(Acat, srcA, et, rs, re, Acat);
  gemm_splitk_kernel<<<(Nn / 128) * 4 * 2, 256, 0, stream>>>(Acat, Bt1, hop, Nn, 512, 2560);
  reduce_ho_kernel<<<Nn * 512 / 2048, 256, 0, stream>>>(hop, hop + (size_t)Nn * 512, b_rgcn, ho);
  gemm256_kernel<<<(Nn / 256) * (2048 >> 8), 512, 0, stream>>>(ho, Bt2, bias2, qkvs, Nn, 2048, 512);
  attn_wave_kernel<<<Nn / 4, 256, 0, stream>>>(qkvs, srcA, rs, re, x, gamma, beta,
                                               (float*)d_out, (float*)d_out + (size_t)Nn * 512);
}

// Round 14
// 110.572 us; speedup vs baseline: 1.5914x; 1.0785x over previous
//
#include <hip/hip_runtime.h>

typedef unsigned short u16;
typedef __attribute__((ext_vector_type(8))) short s16x8;
typedef __attribute__((ext_vector_type(4))) float f32x4;

__device__ __forceinline__ float bf2f(u16 u) {
  union { unsigned int i; float f; } v; v.i = ((unsigned int)u) << 16; return v.f;
}
__device__ __forceinline__ u16 f2bf(float f) {
  union { float f; unsigned int i; } v; v.f = f;
  unsigned int r = (v.i + 0x7FFFu + ((v.i >> 16) & 1u)) >> 16;
  return (u16)r;
}
__device__ __forceinline__ void async16(const void* g, void* l) {
  __builtin_amdgcn_global_load_lds((const __attribute__((address_space(1))) void*)g,
                                   (__attribute__((address_space(3))) void*)l, 16, 0, 0);
}

// ---------------------------------------------------------------------------
// prep: LDS-tiled 64x64 transposes (f32 [K][N] -> bf16 Bt[N][K]), bias concat,
// x -> bf16 tail of Acat (float4), find_ranges folded in as extra blocks.
// ---------------------------------------------------------------------------
__global__ __launch_bounds__(256) void prep_kernel(
    const float* __restrict__ W_rel, const float* __restrict__ W_root,
    const float* __restrict__ Wq, const float* __restrict__ Wk,
    const float* __restrict__ Wv, const float* __restrict__ Wskip,
    const float* __restrict__ bq, const float* __restrict__ bk,
    const float* __restrict__ bv, const float* __restrict__ bskip,
    const float* __restrict__ x,
    u16* __restrict__ Bt1, u16* __restrict__ Bt2, float* __restrict__ bias2,
    u16* __restrict__ Acat, int Nn,
    const int* __restrict__ dst, int E, int* __restrict__ rs, int* __restrict__ re)
{
  const int b = (int)blockIdx.x;
  const int tid = threadIdx.x;
  if (b < 576) {
    __shared__ float tile[64][65];
    const float* S;
    u16* D;
    int ldD;
    long dbase;
    if (b < 320) {
      const int kt = b >> 3, et = b & 7;
      const int r0 = kt * 64, c0 = et * 64;
      S = (r0 < 2048) ? (W_rel + (long)r0 * 512 + c0)
                      : (W_root + (long)(r0 - 2048) * 512 + c0);
      D = Bt1; ldD = 2560; dbase = (long)c0 * 2560 + r0;
    } else {
      const int b2 = b - 320;
      const int jt = b2 >> 3, kt = b2 & 7;
      const int j0 = jt * 64, k0 = kt * 64;
      const int which = j0 >> 9, col0 = j0 & 511;
      const float* W = (which == 0) ? Wq : (which == 1) ? Wk : (which == 2) ? Wv : Wskip;
      S = W + (long)k0 * 512 + col0;
      D = Bt2; ldD = 512; dbase = (long)j0 * 512 + k0;
    }
    const int lc = tid & 63;
#pragma unroll
    for (int i = 0; i < 16; ++i) {
      const int r = (tid >> 6) * 16 + i;
      tile[r][lc] = S[(long)r * 512 + lc];
    }
    __syncthreads();
    const int oc2 = (tid & 31) * 2;
#pragma unroll
    for (int i = 0; i < 8; ++i) {
      const int orow = (tid >> 5) + i * 8;
      const unsigned int pk = (unsigned int)f2bf(tile[oc2][orow]) |
                              ((unsigned int)f2bf(tile[oc2 + 1][orow]) << 16);
      *(unsigned int*)(D + dbase + (long)orow * ldD + oc2) = pk;
    }
  } else if (b == 576) {
#pragma unroll
    for (int i = 0; i < 8; ++i) {
      const int j = tid + i * 256;
      const int which = j >> 9, col = j & 511;
      const float* bb = (which == 0) ? bq : (which == 1) ? bk : (which == 2) ? bv : bskip;
      bias2[j] = bb[col];
    }
  } else if (b < 4673) {
    const long u = ((long)(b - 577) * 256 + tid) * 4;
    if (u < (long)Nn * 512) {
      const float4 v = *(const float4*)(x + u);
      const unsigned int p0 = (unsigned int)f2bf(v.x) | ((unsigned int)f2bf(v.y) << 16);
      const unsigned int p1 = (unsigned int)f2bf(v.z) | ((unsigned int)f2bf(v.w) << 16);
      unsigned int* dp = (unsigned int*)(Acat + ((long)(u >> 9)) * 2560 + 2048 + (u & 511));
      dp[0] = p0; dp[1] = p1;
    }
  } else {
    const int e = (b - 4673) * 256 + tid;
    if (e < E) {
      const int d = dst[e];
      if (e == 0 || dst[e - 1] != d) rs[d] = e;
      if (e == E - 1 || dst[e + 1] != d) re[d] = e + 1;
    }
  }
}

// ---------------------------------------------------------------------------
// RGCN aggregation: 2 nodes/block, 128 threads/node, 4 dims/thread via one
// 8B load per edge (coalescing sweet spot, half the load instructions of the
// 4B/lane version). Register accumulators, XCD-chunked dst swizzle, bf16 in.
// ---------------------------------------------------------------------------
__global__ __launch_bounds__(256) void aggregate_kernel(
    const u16* __restrict__ Acat_ro, const int* __restrict__ src,
    const int* __restrict__ etype, const int* __restrict__ rs,
    const int* __restrict__ re, u16* __restrict__ Acat)
{
  __shared__ int s_src[2][16];
  __shared__ int s_rel[2][16];
  const int q = (int)gridDim.x >> 3;            // 512 (gridDim 4096 % 8 == 0)
  const int bid = (int)blockIdx.x;
  const int blk = (bid & 7) * q + (bid >> 3);   // XCD-chunked
  const int half = threadIdx.x >> 7;            // node within block
  const int l = threadIdx.x & 127;
  const int i = blk * 2 + half;

  const int s0 = rs[i];
  int ne = re[i] - s0;
  if (ne > 16) ne = 16;
  if (l < ne) { s_src[half][l] = src[s0 + l]; s_rel[half][l] = etype[s0 + l]; }
  __syncthreads();

  const int d0 = l * 4;
  float acc[4][4] = {};
  int cnt[4] = {0, 0, 0, 0};
  for (int t = 0; t < ne; ++t) {
    const int sj = s_src[half][t];
    const int rel = s_rel[half][t];
    const uint2 pk = *(const uint2*)(Acat_ro + (long)sj * 2560 + 2048 + d0);
    const float v0 = bf2f((u16)pk.x), v1 = bf2f((u16)(pk.x >> 16));
    const float v2 = bf2f((u16)pk.y), v3 = bf2f((u16)(pk.y >> 16));
#pragma unroll
    for (int r = 0; r < 4; ++r)
      if (rel == r) {
        acc[r][0] += v0; acc[r][1] += v1; acc[r][2] += v2; acc[r][3] += v3;
        cnt[r]++;
      }
  }

  const long base = (long)i * 2560 + d0;
#pragma unroll
  for (int r = 0; r < 4; ++r) {
    const float inv = 1.0f / fmaxf((float)cnt[r], 1.0f);
    uint2 pk;
    pk.x = (unsigned int)f2bf(acc[r][0] * inv) | ((unsigned int)f2bf(acc[r][1] * inv) << 16);
    pk.y = (unsigned int)f2bf(acc[r][2] * inv) | ((unsigned int)f2bf(acc[r][3] * inv) << 16);
    *(uint2*)(Acat + base + r * 512) = pk;
  }
}

// ---------------------------------------------------------------------------
// G1 bf16 GEMM (R10 measured-best config): 128x128 tile, BK=64, 8 waves (2x4),
// 2x32KB dbuf LDS (2 blocks/CU), top-of-iter vmcnt(0) drain, STAGE after
// barrier, setprio, XOR swizzle, XCD-chunked blockIdx swizzle.
// ---------------------------------------------------------------------------
__global__ __launch_bounds__(512, 4) void gemm_bt_kernel(
    const u16* __restrict__ A, const u16* __restrict__ Bt,
    const float* __restrict__ bias, u16* __restrict__ C,
    const int M, const int N, const int K)
{
  __shared__ u16 lds[2][2][128 * 64];   // 2 buf x (A,B) x 16KB = 64 KiB
  const int tid = threadIdx.x;
  const int lane = tid & 63, wid = tid >> 6;
  const int nbn = N >> 7;
  const int q = (int)gridDim.x >> 3;
  const int bid = (int)blockIdx.x;
  const int swz = (bid & 7) * q + (bid >> 3);
  const int bm = swz / nbn, bn = swz % nbn;
  const int wr = wid >> 2, wc = wid & 3;   // 2 x 4 wave grid

  f32x4 acc[4][2] = {};

  const int srow = tid >> 3;   // 0..63
  const int sch = tid & 7;     // physical 16B chunk within 128B row
  const long a_row0 = (long)bm * 128;
  const long b_row0 = (long)bn * 128;
  const int lds_wbase = wid * 512;

  auto STAGE = [&](int buf, int kt) {
#pragma unroll
    for (int it = 0; it < 2; ++it) {
      const int row = it * 64 + srow;
      const int lch = sch ^ (row & 7);
      async16(A  + (a_row0 + row) * K + kt + lch * 8, &lds[buf][0][it * 4096 + lds_wbase]);
      async16(Bt + (b_row0 + row) * K + kt + lch * 8, &lds[buf][1][it * 4096 + lds_wbase]);
    }
  };

  const int nt = K >> 6;
  STAGE(0, 0);
  int cur = 0;
  for (int t = 0; t < nt; ++t) {
    asm volatile("s_waitcnt vmcnt(0)" ::: "memory");
    __builtin_amdgcn_s_barrier();
    if (t + 1 < nt) STAGE(cur ^ 1, (t + 1) << 6);   // overlaps compute below
#pragma unroll
    for (int kk = 0; kk < 2; ++kk) {
      s16x8 af[4], bfr[2];
#pragma unroll
      for (int mi = 0; mi < 4; ++mi) {
        const int row = wr * 64 + mi * 16 + (lane & 15);
        const int cb = (kk * 64 + ((lane >> 4) << 4)) ^ ((row & 7) << 4);
        af[mi] = *(const s16x8*)((const char*)&lds[cur][0][0] + row * 128 + cb);
      }
#pragma unroll
      for (int ni = 0; ni < 2; ++ni) {
        const int row = wc * 32 + ni * 16 + (lane & 15);
        const int cb = (kk * 64 + ((lane >> 4) << 4)) ^ ((row & 7) << 4);
        bfr[ni] = *(const s16x8*)((const char*)&lds[cur][1][0] + row * 128 + cb);
      }
      __builtin_amdgcn_s_setprio(1);
#pragma unroll
      for (int mi = 0; mi < 4; ++mi)
#pragma unroll
        for (int ni = 0; ni < 2; ++ni)
          acc[mi][ni] = __builtin_amdgcn_mfma_f32_16x16x32_bf16(af[mi], bfr[ni], acc[mi][ni], 0, 0, 0);
      __builtin_amdgcn_s_setprio(0);
    }
    cur ^= 1;
  }

#pragma unroll
  for (int mi = 0; mi < 4; ++mi) {
    const int row0 = bm * 128 + wr * 64 + mi * 16 + ((lane >> 4) << 2);
#pragma unroll
    for (int ni = 0; ni < 2; ++ni) {
      const int col = bn * 128 + wc * 32 + ni * 16 + (lane & 15);
      const float bv = bias[col];
#pragma unroll
      for (int j = 0; j < 4; ++j)
        C[(long)(row0 + j) * N + col] = f2bf(acc[mi][ni][j] + bv);
    }
  }
}

// ---------------------------------------------------------------------------
// G2 bf16 GEMM — 8-phase 256² template (R6, measured win). Unchanged.
// ---------------------------------------------------------------------------
__global__ __launch_bounds__(512, 2) void gemm256_kernel(
    const u16* __restrict__ A, const u16* __restrict__ Bt,
    const float* __restrict__ bias, u16* __restrict__ C,
    const int M, const int N, const int K)
{
  __shared__ u16 lds[2][2][256 * 64];   // 2 buf x (A,B) x 32KB = 128 KiB
  const int tid = threadIdx.x;
  const int lane = tid & 63, wid = tid >> 6;
  const int nbn = N >> 8;
  const int q = (int)gridDim.x >> 3;
  const int bid = (int)blockIdx.x;
  const int swz = (bid & 7) * q + (bid >> 3);
  const int bm = swz / nbn, bn = swz % nbn;
  const int wr = wid >> 2, wc = wid & 3;   // 2 x 4 wave grid, wave tile 128x64

  f32x4 acc[8][4] = {};

  const int srow = tid >> 3;   // 0..63
  const int sch = tid & 7;
  const long a_row0 = (long)bm * 256;
  const long b_row0 = (long)bn * 256;
  const int lds_wbase = wid * 512;

  auto STAGE = [&](int buf, int kt) {
#pragma unroll
    for (int it = 0; it < 4; ++it) {
      const int row = it * 64 + srow;              // row & 7 == srow & 7
      const int lch = sch ^ (srow & 7);
      async16(A  + (a_row0 + row) * K + kt + lch * 8, &lds[buf][0][it * 4096 + lds_wbase]);
      async16(Bt + (b_row0 + row) * K + kt + lch * 8, &lds[buf][1][it * 4096 + lds_wbase]);
    }
  };

  const int nt = K >> 6;   // 8 for K=512
  STAGE(0, 0);
  int cur = 0;
  for (int t = 0; t < nt; ++t) {
    asm volatile("s_waitcnt vmcnt(0)" ::: "memory");
    __builtin_amdgcn_s_barrier();
    s16x8 bfr[4][2];
#pragma unroll
    for (int p = 0; p < 4; ++p) {
      s16x8 af[2][2];
#pragma unroll
      for (int i2 = 0; i2 < 2; ++i2) {
        const int row = wr * 128 + (p * 2 + i2) * 16 + (lane & 15);
#pragma unroll
        for (int kk = 0; kk < 2; ++kk) {
          const int cb = (kk * 64 + ((lane >> 4) << 4)) ^ ((row & 7) << 4);
          af[i2][kk] = *(const s16x8*)((const char*)&lds[cur][0][0] + row * 128 + cb);
        }
      }
      if (p == 0) {
#pragma unroll
        for (int ni = 0; ni < 4; ++ni) {
          const int row = wc * 64 + ni * 16 + (lane & 15);
#pragma unroll
          for (int kk = 0; kk < 2; ++kk) {
            const int cb = (kk * 64 + ((lane >> 4) << 4)) ^ ((row & 7) << 4);
            bfr[ni][kk] = *(const s16x8*)((const char*)&lds[cur][1][0] + row * 128 + cb);
          }
        }
        if (t + 1 < nt) STAGE(cur ^ 1, (t + 1) << 6);   // issue-early, drain next iter
      }
      __builtin_amdgcn_s_barrier();
      asm volatile("s_waitcnt lgkmcnt(0)" ::: "memory");
      __builtin_amdgcn_sched_barrier(0);
      __builtin_amdgcn_s_setprio(1);
#pragma unroll
      for (int i2 = 0; i2 < 2; ++i2)
#pragma unroll
        for (int ni = 0; ni < 4; ++ni)
#pragma unroll
          for (int kk = 0; kk < 2; ++kk)
            acc[p * 2 + i2][ni] = __builtin_amdgcn_mfma_f32_16x16x32_bf16(
                af[i2][kk], bfr[ni][kk], acc[p * 2 + i2][ni], 0, 0, 0);
      __builtin_amdgcn_s_setprio(0);
      __builtin_amdgcn_s_barrier();
    }
    cur ^= 1;
  }

#pragma unroll
  for (int mi = 0; mi < 8; ++mi) {
    const int row0 = bm * 256 + wr * 128 + mi * 16 + ((lane >> 4) << 2);
#pragma unroll
    for (int ni = 0; ni < 4; ++ni) {
      const int col = bn * 256 + wc * 64 + ni * 16 + (lane & 15);
      const float bv = bias[col];
#pragma unroll
      for (int j = 0; j < 4; ++j)
        C[(long)(row0 + j) * N + col] = f2bf(acc[mi][ni][j] + bv);
    }
  }
}

// ---------------------------------------------------------------------------
// Wave-per-dst attention + skip + leaky + residual + LayerNorm (R9 win).
// ---------------------------------------------------------------------------
__global__ __launch_bounds__(256) void attn_wave_kernel(
    const u16* __restrict__ qkvs, const int* __restrict__ src,
    const int* __restrict__ rs, const int* __restrict__ re,
    const float* __restrict__ x, const float* __restrict__ gamma,
    const float* __restrict__ beta, float* __restrict__ out,
    float* __restrict__ scl)
{
  __shared__ float sm[4][16];
  __shared__ int s_src[4][16];
  const int bid = (int)blockIdx.x;
  const int tid = threadIdx.x;
  const int lane = tid & 63, wid = tid >> 6;
  const int q = (int)gridDim.x >> 3;            // grid % 8 == 0 (2048)
  const int blk = (bid & 7) * q + (bid >> 3);   // XCD-chunked
  const int i = blk * 4 + wid;                  // this wave's dst node
  if (bid == 0 && tid == 0) scl[0] = 0.0f;      // graph_cl_loss output

  const int s0 = rs[i];
  int ne = re[i] - s0;
  if (ne > 16) ne = 16;
  const int g16 = lane & 15;     // dim-group lane
  const int eg  = lane >> 4;     // edge subgroup 0..3
  if (lane < ne) s_src[wid][lane] = src[s0 + lane];   // same-wave LDS, no barrier

  float qv[32];
#pragma unroll
  for (int c = 0; c < 4; ++c) {
    const s16x8 q8 = *(const s16x8*)(qkvs + (long)i * 2048 + c * 128 + g16 * 8);
#pragma unroll
    for (int u = 0; u < 8; ++u) qv[c * 8 + u] = bf2f((u16)q8[u]);
  }

#pragma unroll
  for (int round = 0; round < 4; ++round) {
    const int e = round * 4 + eg;
    float dp = 0.f;
    if (e < ne) {
      const long rb = (long)s_src[wid][e] * 2048 + 512;
#pragma unroll
      for (int c = 0; c < 4; ++c) {
        const s16x8 k8 = *(const s16x8*)(qkvs + rb + c * 128 + g16 * 8);
#pragma unroll
        for (int u = 0; u < 8; ++u) dp += qv[c * 8 + u] * bf2f((u16)k8[u]);
      }
    }
#pragma unroll
    for (int m = 1; m <= 8; m <<= 1) dp += __shfl_xor(dp, m);
    if (g16 == 0 && e < ne) sm[wid][e] = dp * 0.04419417382415922f;  // 1/sqrt(512)
  }
  {
    const float v = (lane < ne) ? sm[wid][lane] : -1e30f;
    float mx = v;
#pragma unroll
    for (int m = 1; m <= 8; m <<= 1) mx = fmaxf(mx, __shfl_xor(mx, m, 16));
    const float ex = (lane < ne) ? expf(v - mx) : 0.f;
    float den = ex;
#pragma unroll
    for (int m = 1; m <= 8; m <<= 1) den += __shfl_xor(den, m, 16);
    if (lane < ne) sm[wid][lane] = ex / fmaxf(den, 1e-16f);
  }

  const int d8 = lane * 8;
  float a[8] = {};
  for (int e = 0; e < ne; ++e) {
    const float al = sm[wid][e];
    const s16x8 v8 = *(const s16x8*)(qkvs + (long)s_src[wid][e] * 2048 + 1024 + d8);
#pragma unroll
    for (int u = 0; u < 8; ++u) a[u] += al * bf2f((u16)v8[u]);
  }
  const s16x8 sk8 = *(const s16x8*)(qkvs + (long)i * 2048 + 1536 + d8);
  const float4 x0 = *(const float4*)(x + (long)i * 512 + d8);
  const float4 x1 = *(const float4*)(x + (long)i * 512 + d8 + 4);
  float o[8];
  float s = 0.f, s2 = 0.f;
#pragma unroll
  for (int u = 0; u < 8; ++u) {
    float h = a[u] + bf2f((u16)sk8[u]);
    h = (h > 0.f) ? h : 0.01f * h;
    const float xx = (u < 4) ? ((const float*)&x0)[u] : ((const float*)&x1)[u - 4];
    o[u] = xx + h;
    s += o[u];
    s2 += o[u] * o[u];
  }
#pragma unroll
  for (int m = 32; m >= 1; m >>= 1) { s += __shfl_xor(s, m); s2 += __shfl_xor(s2, m); }
  const float mean = s * (1.f / 512.f);
  const float var = s2 * (1.f / 512.f) - mean * mean;
  const float rstd = rsqrtf(var + 1e-5f);
  const float4 g0 = *(const float4*)(gamma + d8), g1 = *(const float4*)(gamma + d8 + 4);
  const float4 b0 = *(const float4*)(beta + d8),  b1 = *(const float4*)(beta + d8 + 4);
  float4 r0, r1;
  r0.x = (o[0] - mean) * rstd * g0.x + b0.x;
  r0.y = (o[1] - mean) * rstd * g0.y + b0.y;
  r0.z = (o[2] - mean) * rstd * g0.z + b0.z;
  r0.w = (o[3] - mean) * rstd * g0.w + b0.w;
  r1.x = (o[4] - mean) * rstd * g1.x + b1.x;
  r1.y = (o[5] - mean) * rstd * g1.y + b1.y;
  r1.z = (o[6] - mean) * rstd * g1.z + b1.z;
  r1.w = (o[7] - mean) * rstd * g1.w + b1.w;
  *(float4*)(out + (long)i * 512 + d8) = r0;
  *(float4*)(out + (long)i * 512 + d8 + 4) = r1;
}

// ---------------------------------------------------------------------------
extern "C" void kernel_launch(void* const* d_in, const int* in_sizes, int n_in,
                              void* d_out, int out_size, void* d_ws, size_t ws_size,
                              hipStream_t stream) {
  const float* x      = (const float*)d_in[0];
  const int*   ei     = (const int*)d_in[1];
  const int*   et     = (const int*)d_in[2];
  const float* W_rel  = (const float*)d_in[3];
  const float* W_root = (const float*)d_in[4];
  const float* b_rgcn = (const float*)d_in[5];
  const float* Wq     = (const float*)d_in[6];
  const float* bq     = (const float*)d_in[7];
  const float* Wk     = (const float*)d_in[8];
  const float* bk     = (const float*)d_in[9];
  const float* Wv     = (const float*)d_in[10];
  const float* bv     = (const float*)d_in[11];
  const float* Wskip  = (const float*)d_in[12];
  const float* bskip  = (const float*)d_in[13];
  const float* gamma  = (const float*)d_in[14];
  const float* beta   = (const float*)d_in[15];
  const int E  = in_sizes[2];
  const int Nn = in_sizes[0] / 512;           // 8192
  const int* srcA = ei;
  const int* dstA = ei + E;

  char* p = (char*)d_ws;
  u16* Acat   = (u16*)p;   p += (size_t)Nn * 2560 * 2;   // [N][2560] bf16
  u16* Bt1    = (u16*)p;   p += (size_t)512 * 2560 * 2;  // [512][2560] bf16
  u16* Bt2    = (u16*)p;   p += (size_t)2048 * 512 * 2;  // [2048][512] bf16
  float* bias2= (float*)p; p += (size_t)2048 * 4;
  u16* ho     = (u16*)p;   p += (size_t)Nn * 512 * 2;
  u16* qkvs   = (u16*)p;   p += (size_t)Nn * 2048 * 2;
  int* rs     = (int*)p;   p += (size_t)Nn * 4;
  int* re     = (int*)p;   p += (size_t)Nn * 4;

  const int FB = (E + 255) / 256;
  const int prep_blocks = 4673 + FB;

  prep_kernel<<<prep_blocks, 256, 0, stream>>>(W_rel, W_root, Wq, Wk, Wv, Wskip,
                                               bq, bk, bv, bskip, x, Bt1, Bt2, bias2, Acat, Nn,
                                               dstA, E, rs, re);
  aggregate_kernel<<<Nn / 2, 256, 0, stream>>>(Acat, srcA, et, rs, re, Acat);
  gemm_bt_kernel<<<(Nn / 128) * (512 >> 7), 512, 0, stream>>>(Acat, Bt1, b_rgcn, ho, Nn, 512, 2560);
  gemm256_kernel<<<(Nn / 256) * (2048 >> 8), 512, 0, stream>>>(ho, Bt2, bias2, qkvs, Nn, 2048, 512);
  attn_wave_kernel<<<Nn / 4, 256, 0, stream>>>(qkvs, srcA, rs, re, x, gamma, beta,
                                               (float*)d_out, (float*)d_out + (size_t)Nn * 512);
}